// Round 3
// baseline (617.900 us; speedup 1.0000x reference)
//
#include <hip/hip_runtime.h>

#define N_NODES 50000
#define N_EDGES 400000
#define CSR_E (2 * N_EDGES + N_NODES) /* 850000 */
#define OUT_N (N_NODES * 64)

typedef unsigned short ushort_t;
typedef unsigned int uint_t;

__device__ __forceinline__ float bf2f(ushort_t u) {
    return __uint_as_float(((uint_t)u) << 16);
}
__device__ __forceinline__ ushort_t f2bf(float f) {
    uint_t b = __float_as_uint(f);
    b += 0x7FFFu + ((b >> 16) & 1u); // RNE
    return (ushort_t)(b >> 16);
}

// ---------------- static device scratch (module BSS; d_ws untouched) ----------------

__device__ int g_est;  // edge-index word stride: 1 = int32 layout, 2 = int64 layout
__device__ int g_is16; // 1 = float tensors are bf16-packed, 0 = fp32
__device__ float g_deg_s[N_NODES];
__device__ float g_deg_r[N_NODES];
__device__ float g_dis_s[N_NODES];
__device__ float g_dis_r[N_NODES];
__device__ float g_c2[N_EDGES];
__device__ float g_s2[N_EDGES];
__device__ int g_count[N_NODES];
__device__ int g_offs[N_NODES];
__device__ int g_cursor[N_NODES];
__device__ int g_bsum[64];
__device__ int g_bbase[64];
__device__ __align__(16) float4 g_csr[CSR_E];                  // (src_bits, wS, wD, 0)
__device__ __align__(16) float g_agg[(size_t)N_NODES * 256];   // fp32 [N][s(128)|d(128)]
__device__ __align__(16) float g_h1[(size_t)N_NODES * 128];
__device__ __align__(16) float g_h2[(size_t)N_NODES * 128];
__device__ __align__(16) float g_wc1[256 * 128];
__device__ __align__(16) float g_wc2[256 * 128];
__device__ __align__(16) float g_wro[128 * 64];
__device__ float g_bc1[128];
__device__ float g_bc2[128];
__device__ float g_bro[64];

// ---------------- dtype / index-width detection ----------------

__global__ void detect_kernel(const uint_t* __restrict__ xw, const int* __restrict__ eidx) {
    if (threadIdx.x == 0 && blockIdx.x == 0) {
        // bf16-packed vs fp32: low 16 bits of each word. For bf16-packed x~N(0,1),
        // the low half is a real bf16 with exponent near 127. For fp32, those bits
        // are uniform mantissa bits (exponent-field-in-window prob ~0.2).
        int cnt = 0;
        for (int i = 0; i < 64; i++) {
            uint_t w = xw[i];
            int elo = (w >> 7) & 0xFF;
            if (elo >= 100 && elo <= 150) cnt++;
        }
        g_is16 = (cnt >= 48) ? 1 : 0;
        // int64 vs int32: odd words all zero => int64 high halves
        int any = 0;
        for (int i = 1; i < 128; i += 2) any |= eidx[i];
        g_est = any ? 1 : 2;
    }
}

// ---------------- sentinel: prove kernels execute; fully overwritten by readout ----------------

__global__ __launch_bounds__(256) void sentinel_kernel(void* outp) {
    int i = blockIdx.x * 256 + threadIdx.x;
    if (i >= OUT_N) return;
    if (g_is16)
        ((ushort_t*)outp)[i] = f2bf(333.0f);
    else
        ((float*)outp)[i] = 333.0f;
}

// ---------------- graph prep ----------------

__global__ __launch_bounds__(256) void init_nodes() {
    int i = blockIdx.x * 256 + threadIdx.x;
    if (i < N_NODES) {
        g_deg_s[i] = 1.0f; // self-loop out_w
        g_deg_r[i] = 1.0f; // self-loop in_w
        g_count[i] = 1;    // self-loop CSR entry
    }
}

__global__ __launch_bounds__(256) void edge_pass(const int* __restrict__ eidx,
                                                 const ushort_t* __restrict__ th16,
                                                 const float* __restrict__ th32) {
    int e = blockIdx.x * 256 + threadIdx.x;
    if (e >= N_EDGES) return;
    int st = g_est;
    int s = eidx[(size_t)e * st];
    int r = eidx[((size_t)N_EDGES + e) * st];
    float t = g_is16 ? bf2f(th16[e]) : th32[e];
    float sn, cs_;
    sincosf(t, &sn, &cs_);
    float c2 = cs_ * cs_;
    float s2 = sn * sn;
    g_c2[e] = c2;
    g_s2[e] = s2;
    // deg_s = segsum(out_w keyed by cs): (cs=s,c2),(cs=r,s2)
    // deg_r = segsum(in_w  keyed by cs): (cs=s,s2),(cs=r,c2)
    atomicAdd(&g_deg_s[s], c2);
    atomicAdd(&g_deg_s[r], s2);
    atomicAdd(&g_deg_r[s], s2);
    atomicAdd(&g_deg_r[r], c2);
    // CSR keyed by destination cr: fwd entry dst=r, rev entry dst=s
    atomicAdd(&g_count[r], 1);
    atomicAdd(&g_count[s], 1);
}

__global__ __launch_bounds__(256) void node_pass() {
    int i = blockIdx.x * 256 + threadIdx.x;
    if (i >= N_NODES) return;
    // deg <= 850001 always; reference's >1e11 branch never fires
    g_dis_s[i] = rsqrtf(g_deg_s[i] + 1e-12f);
    g_dis_r[i] = rsqrtf(g_deg_r[i] + 1e-12f);
}

// ---------------- exclusive scan over counts ----------------

__global__ __launch_bounds__(1024) void scan1() {
    __shared__ int sd[1024];
    int i = blockIdx.x * 1024 + threadIdx.x;
    int v = (i < N_NODES) ? g_count[i] : 0;
    sd[threadIdx.x] = v;
    __syncthreads();
    for (int o = 1; o < 1024; o <<= 1) {
        int tv = (threadIdx.x >= o) ? sd[threadIdx.x - o] : 0;
        __syncthreads();
        sd[threadIdx.x] += tv;
        __syncthreads();
    }
    if (i < N_NODES) g_offs[i] = sd[threadIdx.x] - v; // exclusive, block-local
    if (threadIdx.x == 1023) g_bsum[blockIdx.x] = sd[1023];
}

__global__ void scan2(int nb) {
    if (blockIdx.x == 0 && threadIdx.x == 0) {
        int run = 0;
        for (int b = 0; b < nb; b++) {
            g_bbase[b] = run;
            run += g_bsum[b];
        }
    }
}

__global__ __launch_bounds__(256) void scan3() {
    int i = blockIdx.x * 256 + threadIdx.x;
    if (i < N_NODES) {
        int o = g_offs[i] + g_bbase[i >> 10];
        g_offs[i] = o;
        g_cursor[i] = o;
    }
}

// ---------------- CSR fill (ALPHA=0.5 folded) ----------------

__global__ __launch_bounds__(256) void fill_edges(const int* __restrict__ eidx) {
    int e = blockIdx.x * 256 + threadIdx.x;
    if (e >= N_EDGES) return;
    int st = g_est;
    int s = eidx[(size_t)e * st];
    int r = eidx[((size_t)N_EDGES + e) * st];
    float c2 = g_c2[e], s2 = g_s2[e];
    float dss = g_dis_s[s], dsr = g_dis_s[r], drs = g_dis_r[s], drr = g_dis_r[r];
    // forward entry: cs=s, cr=r, out_w=c2, in_w=s2
    {
        float wS = dss * c2 * drr * 0.5f; // dis_s[cs]*out_w*dis_r[cr]
        float wD = drs * s2 * dsr * 0.5f; // dis_r[cs]*in_w*dis_s[cr]
        int p = atomicAdd(&g_cursor[r], 1);
        g_csr[p] = make_float4(__int_as_float(s), wS, wD, 0.0f);
    }
    // reverse entry: cs=r, cr=s, out_w=s2, in_w=c2
    {
        float wS = dsr * s2 * drs * 0.5f;
        float wD = drr * c2 * dss * 0.5f;
        int p = atomicAdd(&g_cursor[s], 1);
        g_csr[p] = make_float4(__int_as_float(r), wS, wD, 0.0f);
    }
}

__global__ __launch_bounds__(256) void fill_self() {
    int n = blockIdx.x * 256 + threadIdx.x;
    if (n >= N_NODES) return;
    float w = g_dis_s[n] * g_dis_r[n] * 0.5f;
    int p = atomicAdd(&g_cursor[n], 1);
    g_csr[p] = make_float4(__int_as_float(n), w, w, 0.0f);
}

// ---------------- weight prep (dtype-flex -> fp32) ----------------

__global__ __launch_bounds__(256) void prep_wc(const ushort_t* Ws16, const float* Ws32,
                                               const ushort_t* Wd16, const float* Wd32,
                                               const ushort_t* bs16, const float* bs32,
                                               const ushort_t* bd16, const float* bd32,
                                               int layer) {
    float* Wc = layer ? g_wc2 : g_wc1;
    float* bc = layer ? g_bc2 : g_bc1;
    int is16 = g_is16;
    int i = blockIdx.x * 256 + threadIdx.x;
    if (i < 256 * 128) {
        int k = i >> 7, j = i & 127;
        float v;
        if (k < 128) {
            int idx = k * 128 + j;
            v = is16 ? bf2f(Ws16[idx]) : Ws32[idx];
        } else {
            int idx = (k - 128) * 128 + j;
            v = is16 ? bf2f(Wd16[idx]) : Wd32[idx];
        }
        Wc[i] = v;
    }
    if (i < 128) {
        float a = is16 ? bf2f(bs16[i]) : bs32[i];
        float b = is16 ? bf2f(bd16[i]) : bd32[i];
        bc[i] = 0.5f * (a + b);
    }
}

__global__ __launch_bounds__(256) void prep_ro(const ushort_t* W16, const float* W32,
                                               const ushort_t* b16, const float* b32) {
    int is16 = g_is16;
    int i = blockIdx.x * 256 + threadIdx.x;
    if (i < 128 * 64) g_wro[i] = is16 ? bf2f(W16[i]) : W32[i];
    if (i < 64) g_bro[i] = is16 ? bf2f(b16[i]) : b32[i];
}

// ---------------- aggregation: one wave per node, lane owns 2 features ----------------
// ext=1: input is external x (dtype-flex). ext=0: input g_h1 (fp32). Output g_agg fp32 [N][256].

__global__ __launch_bounds__(256) void aggregate_kernel(const ushort_t* __restrict__ x16,
                                                        const float* __restrict__ x32, int ext) {
    int node = blockIdx.x * 4 + (threadIdx.x >> 6);
    if (node >= N_NODES) return;
    int lane = threadIdx.x & 63;
    int off = g_offs[node];
    int c = g_count[node];
    float s0 = 0.f, s1 = 0.f, d0 = 0.f, d1 = 0.f;
    if (ext && g_is16) {
        for (int k = 0; k < c; k++) {
            float4 m = g_csr[off + k];
            int src = __float_as_int(m.x);
            uint_t v = *(const uint_t*)(x16 + (size_t)src * 128 + lane * 2);
            float x0 = bf2f((ushort_t)(v & 0xffffu));
            float x1 = bf2f((ushort_t)(v >> 16));
            s0 = fmaf(m.y, x0, s0);
            s1 = fmaf(m.y, x1, s1);
            d0 = fmaf(m.z, x0, d0);
            d1 = fmaf(m.z, x1, d1);
        }
    } else {
        const float* xin = ext ? x32 : g_h1;
        for (int k = 0; k < c; k++) {
            float4 m = g_csr[off + k];
            int src = __float_as_int(m.x);
            float2 xv = *(const float2*)(xin + (size_t)src * 128 + lane * 2);
            s0 = fmaf(m.y, xv.x, s0);
            s1 = fmaf(m.y, xv.y, s1);
            d0 = fmaf(m.z, xv.x, d0);
            d1 = fmaf(m.z, xv.y, d1);
        }
    }
    *(float2*)(g_agg + (size_t)node * 256 + lane * 2) = make_float2(s0, s1);
    *(float2*)(g_agg + (size_t)node * 256 + 128 + lane * 2) = make_float2(d0, d1);
}

// ---------------- tiled fp32 GEMM ----------------
// layer 0: g_h1 = relu(g_agg[50000x256] @ g_wc1[256x128] + g_bc1)
// layer 1: g_h2 = relu(g_agg @ g_wc2 + g_bc2)
// layer 2: out  = g_h2[50000x128] @ g_wro[128x64] + g_bro   (dtype-flex store)

__global__ __launch_bounds__(256) void gemm_kernel(int layer, void* outp) {
    const float* A;
    const float* B;
    const float* bias;
    float* C = nullptr;
    int N, K, relu;
    if (layer == 0) {
        A = g_agg; B = g_wc1; bias = g_bc1; C = g_h1; N = 128; K = 256; relu = 1;
    } else if (layer == 1) {
        A = g_agg; B = g_wc2; bias = g_bc2; C = g_h2; N = 128; K = 256; relu = 1;
    } else {
        A = g_h2; B = g_wro; bias = g_bro; N = 64; K = 128; relu = 0;
    }
    const int M = N_NODES;

    __shared__ float As[64][33];
    __shared__ float Bs[32][64];
    int t = threadIdx.x;
    int tx = t & 15, ty = t >> 4;
    int m0 = blockIdx.x * 64;
    int n0 = blockIdx.y * 64;
    float acc[4][4] = {{0.f}};

    int arow = t >> 2; // 0..63
    int acg = t & 3;   // col group of 8 floats

    for (int kt = 0; kt < K; kt += 32) {
        {
            int rg = m0 + arow;
            const float* ap = A + (size_t)rg * K + kt + acg * 8;
            float4 v0 = make_float4(0, 0, 0, 0), v1 = make_float4(0, 0, 0, 0);
            if (rg < M) {
                v0 = *(const float4*)ap;
                v1 = *(const float4*)(ap + 4);
            }
            int cb = acg * 8;
            As[arow][cb + 0] = v0.x; As[arow][cb + 1] = v0.y;
            As[arow][cb + 2] = v0.z; As[arow][cb + 3] = v0.w;
            As[arow][cb + 4] = v1.x; As[arow][cb + 5] = v1.y;
            As[arow][cb + 6] = v1.z; As[arow][cb + 7] = v1.w;
        }
        {
#pragma unroll
            for (int i = 0; i < 2; i++) {
                int idx = t + i * 256;
                int br = idx >> 4;
                int bc4 = idx & 15;
                float4 v = *(const float4*)(B + (size_t)(kt + br) * N + n0 + bc4 * 4);
                *(float4*)&Bs[br][bc4 * 4] = v;
            }
        }
        __syncthreads();
#pragma unroll
        for (int kk = 0; kk < 32; kk++) {
            float a0 = As[ty * 4 + 0][kk];
            float a1 = As[ty * 4 + 1][kk];
            float a2 = As[ty * 4 + 2][kk];
            float a3 = As[ty * 4 + 3][kk];
            float4 b = *(float4*)&Bs[kk][tx * 4];
            acc[0][0] = fmaf(a0, b.x, acc[0][0]);
            acc[0][1] = fmaf(a0, b.y, acc[0][1]);
            acc[0][2] = fmaf(a0, b.z, acc[0][2]);
            acc[0][3] = fmaf(a0, b.w, acc[0][3]);
            acc[1][0] = fmaf(a1, b.x, acc[1][0]);
            acc[1][1] = fmaf(a1, b.y, acc[1][1]);
            acc[1][2] = fmaf(a1, b.z, acc[1][2]);
            acc[1][3] = fmaf(a1, b.w, acc[1][3]);
            acc[2][0] = fmaf(a2, b.x, acc[2][0]);
            acc[2][1] = fmaf(a2, b.y, acc[2][1]);
            acc[2][2] = fmaf(a2, b.z, acc[2][2]);
            acc[2][3] = fmaf(a2, b.w, acc[2][3]);
            acc[3][0] = fmaf(a3, b.x, acc[3][0]);
            acc[3][1] = fmaf(a3, b.y, acc[3][1]);
            acc[3][2] = fmaf(a3, b.z, acc[3][2]);
            acc[3][3] = fmaf(a3, b.w, acc[3][3]);
        }
        __syncthreads();
    }

    int c0 = n0 + tx * 4;
    float4 bi = *(const float4*)(bias + c0);
#pragma unroll
    for (int i = 0; i < 4; i++) {
        int rg = m0 + ty * 4 + i;
        if (rg >= M) continue;
        float v0 = acc[i][0] + bi.x;
        float v1 = acc[i][1] + bi.y;
        float v2 = acc[i][2] + bi.z;
        float v3 = acc[i][3] + bi.w;
        if (relu) {
            v0 = fmaxf(v0, 0.f);
            v1 = fmaxf(v1, 0.f);
            v2 = fmaxf(v2, 0.f);
            v3 = fmaxf(v3, 0.f);
        }
        if (layer < 2) {
            *(float4*)(C + (size_t)rg * N + c0) = make_float4(v0, v1, v2, v3);
        } else if (g_is16) {
            ushort4 o;
            o.x = f2bf(v0); o.y = f2bf(v1); o.z = f2bf(v2); o.w = f2bf(v3);
            *(ushort4*)((ushort_t*)outp + (size_t)rg * 64 + c0) = o;
        } else {
            *(float4*)((float*)outp + (size_t)rg * 64 + c0) = make_float4(v0, v1, v2, v3);
        }
    }
}

// ---------------- launch ----------------

static inline int cdiv(int a, int b) { return (a + b - 1) / b; }

extern "C" void kernel_launch(void* const* d_in, const int* in_sizes, int n_in,
                              void* d_out, int out_size, void* d_ws, size_t ws_size,
                              hipStream_t stream) {
    const void* x = d_in[0];      // [50000][128] fp32 or bf16
    const int* eidx = (const int*)d_in[1];
    const void* theta = d_in[2];  // [400000]
    const void* W1s = d_in[3];
    const void* W1d = d_in[4];
    const void* b1s = d_in[5];
    const void* b1d = d_in[6];
    const void* W2s = d_in[7];
    const void* W2d = d_in[8];
    const void* b2s = d_in[9];
    const void* b2d = d_in[10];
    const void* Wro = d_in[11];
    const void* bro = d_in[12];
    (void)in_sizes; (void)n_in; (void)out_size; (void)d_ws; (void)ws_size;

    const int NB = cdiv(N_NODES, 1024); // 49

    detect_kernel<<<1, 64, 0, stream>>>((const uint_t*)x, eidx);
    sentinel_kernel<<<cdiv(OUT_N, 256), 256, 0, stream>>>(d_out);
    init_nodes<<<cdiv(N_NODES, 256), 256, 0, stream>>>();
    edge_pass<<<cdiv(N_EDGES, 256), 256, 0, stream>>>(eidx, (const ushort_t*)theta, (const float*)theta);
    node_pass<<<cdiv(N_NODES, 256), 256, 0, stream>>>();
    scan1<<<NB, 1024, 0, stream>>>();
    scan2<<<1, 1, 0, stream>>>(NB);
    scan3<<<cdiv(N_NODES, 256), 256, 0, stream>>>();
    fill_edges<<<cdiv(N_EDGES, 256), 256, 0, stream>>>(eidx);
    fill_self<<<cdiv(N_NODES, 256), 256, 0, stream>>>();
    prep_wc<<<cdiv(256 * 128, 256), 256, 0, stream>>>((const ushort_t*)W1s, (const float*)W1s,
                                                      (const ushort_t*)W1d, (const float*)W1d,
                                                      (const ushort_t*)b1s, (const float*)b1s,
                                                      (const ushort_t*)b1d, (const float*)b1d, 0);
    prep_wc<<<cdiv(256 * 128, 256), 256, 0, stream>>>((const ushort_t*)W2s, (const float*)W2s,
                                                      (const ushort_t*)W2d, (const float*)W2d,
                                                      (const ushort_t*)b2s, (const float*)b2s,
                                                      (const ushort_t*)b2d, (const float*)b2d, 1);
    prep_ro<<<cdiv(128 * 64, 256), 256, 0, stream>>>((const ushort_t*)Wro, (const float*)Wro,
                                                     (const ushort_t*)bro, (const float*)bro);

    // layer 1
    aggregate_kernel<<<cdiv(N_NODES, 4), 256, 0, stream>>>((const ushort_t*)x, (const float*)x, 1);
    gemm_kernel<<<dim3(cdiv(N_NODES, 64), 2), 256, 0, stream>>>(0, nullptr);
    // layer 2
    aggregate_kernel<<<cdiv(N_NODES, 4), 256, 0, stream>>>(nullptr, nullptr, 0);
    gemm_kernel<<<dim3(cdiv(N_NODES, 64), 2), 256, 0, stream>>>(1, nullptr);
    // readout
    gemm_kernel<<<dim3(cdiv(N_NODES, 64), 1), 256, 0, stream>>>(2, d_out);
}

// Round 5
// 466.624 us; speedup vs baseline: 1.3242x; 1.3242x over previous
//
#include <hip/hip_runtime.h>

#define N_NODES 50000
#define N_EDGES 400000
#define CSR_E (2 * N_EDGES + N_NODES) /* 850000 */
#define OUT_N (N_NODES * 64)

typedef unsigned short ushort_t;
typedef unsigned int uint_t;
typedef __attribute__((ext_vector_type(8))) short bf16x8;
typedef __attribute__((ext_vector_type(4))) float f32x4;

__device__ __forceinline__ float bf2f(ushort_t u) {
    return __uint_as_float(((uint_t)u) << 16);
}
__device__ __forceinline__ ushort_t f2bf(float f) {
    uint_t b = __float_as_uint(f);
    b += 0x7FFFu + ((b >> 16) & 1u); // RNE
    return (ushort_t)(b >> 16);
}

// ---------------- static device scratch (module BSS; d_ws untouched) ----------------
// NOTE: these symbols must ONLY be referenced from device code. Passing them as
// kernel arguments from host passes the host shadow address -> GPU fault (round 4).

__device__ int g_est;  // edge-index word stride: 1 = int32, 2 = int64
__device__ int g_is16; // 1 = float tensors bf16-packed, 0 = fp32
__device__ float g_dis_s[N_NODES];
__device__ float g_dis_r[N_NODES];
__device__ float g_c2[N_EDGES];
__device__ float g_s2[N_EDGES];
__device__ int g_count[N_NODES];
__device__ int g_offs[N_NODES];
__device__ int g_cursor[N_NODES];
__device__ int g_bsum[64];
__device__ int g_bbase[64];
__device__ __align__(16) float4 g_csr[CSR_E]; // raw: (src,out,in,dst) -> final: (src,wS,wD,0)
__device__ __align__(16) ushort_t g_agg[(size_t)N_NODES * 256]; // bf16 [N][s128|d128]
__device__ __align__(16) ushort_t g_h1[(size_t)N_NODES * 128];  // bf16
__device__ __align__(16) ushort_t g_h2[(size_t)N_NODES * 128];  // bf16
__device__ __align__(16) ushort_t g_bp1[8 * 128 * 32]; // B packed [kb][n][kk] bf16
__device__ __align__(16) ushort_t g_bp2[8 * 128 * 32];
__device__ __align__(16) ushort_t g_bp3[4 * 64 * 32];
__device__ float g_bc1[128];
__device__ float g_bc2[128];
__device__ float g_bro[64];

// ---------------- dtype / index-width detection ----------------

__global__ void detect_kernel(const uint_t* __restrict__ xw, const int* __restrict__ eidx) {
    if (threadIdx.x == 0 && blockIdx.x == 0) {
        int cnt = 0;
        for (int i = 0; i < 64; i++) {
            uint_t w = xw[i];
            int elo = (w >> 7) & 0xFF;
            if (elo >= 100 && elo <= 150) cnt++;
        }
        g_is16 = (cnt >= 48) ? 1 : 0;
        int any = 0;
        for (int i = 1; i < 128; i += 2) any |= eidx[i];
        g_est = any ? 1 : 2;
    }
}

// ---------------- graph prep ----------------

__global__ __launch_bounds__(256) void init_nodes() {
    int i = blockIdx.x * 256 + threadIdx.x;
    if (i < N_NODES) g_count[i] = 1; // self-loop entry
}

__global__ __launch_bounds__(256) void edge_pass(const int* __restrict__ eidx,
                                                 const ushort_t* __restrict__ th16,
                                                 const float* __restrict__ th32) {
    int e = blockIdx.x * 256 + threadIdx.x;
    if (e >= N_EDGES) return;
    int st = g_est;
    int s = eidx[(size_t)e * st];
    int r = eidx[((size_t)N_EDGES + e) * st];
    float t = g_is16 ? bf2f(th16[e]) : th32[e];
    float sn, cs_;
    sincosf(t, &sn, &cs_);
    g_c2[e] = cs_ * cs_;
    g_s2[e] = sn * sn;
    // CSR bucket sizes keyed by destination cr: fwd dst=r, rev dst=s
    atomicAdd(&g_count[r], 1);
    atomicAdd(&g_count[s], 1);
}

// ---------------- exclusive scan over counts ----------------

__global__ __launch_bounds__(1024) void scan1() {
    __shared__ int sd[1024];
    int i = blockIdx.x * 1024 + threadIdx.x;
    int v = (i < N_NODES) ? g_count[i] : 0;
    sd[threadIdx.x] = v;
    __syncthreads();
    for (int o = 1; o < 1024; o <<= 1) {
        int tv = (threadIdx.x >= o) ? sd[threadIdx.x - o] : 0;
        __syncthreads();
        sd[threadIdx.x] += tv;
        __syncthreads();
    }
    if (i < N_NODES) g_offs[i] = sd[threadIdx.x] - v;
    if (threadIdx.x == 1023) g_bsum[blockIdx.x] = sd[1023];
}

__global__ void scan2(int nb) {
    if (blockIdx.x == 0 && threadIdx.x == 0) {
        int run = 0;
        for (int b = 0; b < nb; b++) {
            g_bbase[b] = run;
            run += g_bsum[b];
        }
    }
}

__global__ __launch_bounds__(256) void scan3() {
    int i = blockIdx.x * 256 + threadIdx.x;
    if (i < N_NODES) {
        int o = g_offs[i] + g_bbase[i >> 10];
        g_offs[i] = o;
        g_cursor[i] = o;
    }
}

// ---------------- raw CSR fill: (src, out_w, in_w, dst) ----------------

__global__ __launch_bounds__(256) void fill_raw(const int* __restrict__ eidx) {
    int e = blockIdx.x * 256 + threadIdx.x;
    if (e >= N_EDGES) return;
    int st = g_est;
    int s = eidx[(size_t)e * st];
    int r = eidx[((size_t)N_EDGES + e) * st];
    float c2 = g_c2[e], s2 = g_s2[e];
    // fwd: cs=s, cr=r, out=c2, in=s2
    {
        int p = atomicAdd(&g_cursor[r], 1);
        g_csr[p] = make_float4(__int_as_float(s), c2, s2, __int_as_float(r));
    }
    // rev: cs=r, cr=s, out=s2, in=c2
    {
        int p = atomicAdd(&g_cursor[s], 1);
        g_csr[p] = make_float4(__int_as_float(r), s2, c2, __int_as_float(s));
    }
}

__global__ __launch_bounds__(256) void fill_self() {
    int n = blockIdx.x * 256 + threadIdx.x;
    if (n >= N_NODES) return;
    int p = atomicAdd(&g_cursor[n], 1);
    g_csr[p] = make_float4(__int_as_float(n), 1.0f, 1.0f, __int_as_float(n));
}

// ---------------- degrees from buckets (atomic-free) ----------------
// pairing identity: deg_s[n] = sum of in_w over bucket n; deg_r[n] = sum of out_w.

__global__ __launch_bounds__(256) void deg_pass() {
    int n = blockIdx.x * 256 + threadIdx.x;
    if (n >= N_NODES) return;
    int off = g_offs[n], c = g_count[n];
    float ds = 0.f, dr = 0.f;
    for (int k = 0; k < c; k++) {
        float4 e = g_csr[off + k];
        ds += e.z; // in_w
        dr += e.y; // out_w
    }
    g_dis_s[n] = rsqrtf(ds + 1e-12f);
    g_dis_r[n] = rsqrtf(dr + 1e-12f);
}

// ---------------- finalize per-entry weights (ALPHA=0.5 folded) ----------------

__global__ __launch_bounds__(256) void finalize_w() {
    int i = blockIdx.x * 256 + threadIdx.x;
    if (i >= CSR_E) return;
    float4 e = g_csr[i];
    int m = __float_as_int(e.x); // src (cs)
    int n = __float_as_int(e.w); // dst (cr)
    float wS = 0.5f * g_dis_s[m] * e.y * g_dis_r[n];
    float wD = 0.5f * g_dis_r[m] * e.z * g_dis_s[n];
    g_csr[i] = make_float4(e.x, wS, wD, 0.0f);
}

// ---------------- weight packing for MFMA: Bp[kb][n][kk] bf16 ----------------

__global__ __launch_bounds__(256) void prep_wc(const ushort_t* Ws16, const float* Ws32,
                                               const ushort_t* Wd16, const float* Wd32,
                                               const ushort_t* bs16, const float* bs32,
                                               const ushort_t* bd16, const float* bd32,
                                               int layer) {
    ushort_t* Bp = layer ? g_bp2 : g_bp1;
    float* bc = layer ? g_bc2 : g_bc1;
    int is16 = g_is16;
    int i = blockIdx.x * 256 + threadIdx.x;
    if (i < 256 * 128) {
        int k = i >> 7, n = i & 127;
        ushort_t v;
        if (k < 128) {
            int idx = k * 128 + n;
            v = is16 ? Ws16[idx] : f2bf(Ws32[idx]);
        } else {
            int idx = (k - 128) * 128 + n;
            v = is16 ? Wd16[idx] : f2bf(Wd32[idx]);
        }
        int kb = k >> 5, kk = k & 31;
        Bp[((kb * 128 + n) << 5) + kk] = v;
    }
    if (i < 128) {
        float a = is16 ? bf2f(bs16[i]) : bs32[i];
        float b = is16 ? bf2f(bd16[i]) : bd32[i];
        bc[i] = 0.5f * (a + b);
    }
}

__global__ __launch_bounds__(256) void prep_ro(const ushort_t* W16, const float* W32,
                                               const ushort_t* b16, const float* b32) {
    int is16 = g_is16;
    int i = blockIdx.x * 256 + threadIdx.x;
    if (i < 128 * 64) {
        int k = i >> 6, n = i & 63;
        ushort_t v = is16 ? W16[i] : f2bf(W32[i]);
        int kb = k >> 5, kk = k & 31;
        g_bp3[((kb * 64 + n) << 5) + kk] = v;
    }
    if (i < 64) g_bro[i] = is16 ? bf2f(b16[i]) : b32[i];
}

// ---------------- aggregation: one wave per node, lane owns 2 features ----------------
// ext=1: input external x (dtype-flex); ext=0: input g_h1 (bf16). Output g_agg bf16 [N][256].

__global__ __launch_bounds__(256) void aggregate_kernel(const ushort_t* __restrict__ x16,
                                                        const float* __restrict__ x32, int ext) {
    int node = blockIdx.x * 4 + (threadIdx.x >> 6);
    if (node >= N_NODES) return;
    int lane = threadIdx.x & 63;
    int off = g_offs[node];
    int c = g_count[node];
    float s0 = 0.f, s1 = 0.f, d0 = 0.f, d1 = 0.f;
    if (!ext || g_is16) {
        const ushort_t* xin = ext ? x16 : g_h1;
        for (int k = 0; k < c; k++) {
            float4 m = g_csr[off + k];
            int src = __float_as_int(m.x);
            uint_t v = *(const uint_t*)(xin + (size_t)src * 128 + lane * 2);
            float x0 = bf2f((ushort_t)(v & 0xffffu));
            float x1 = bf2f((ushort_t)(v >> 16));
            s0 = fmaf(m.y, x0, s0);
            s1 = fmaf(m.y, x1, s1);
            d0 = fmaf(m.z, x0, d0);
            d1 = fmaf(m.z, x1, d1);
        }
    } else {
        for (int k = 0; k < c; k++) {
            float4 m = g_csr[off + k];
            int src = __float_as_int(m.x);
            float2 xv = *(const float2*)(x32 + (size_t)src * 128 + lane * 2);
            s0 = fmaf(m.y, xv.x, s0);
            s1 = fmaf(m.y, xv.y, s1);
            d0 = fmaf(m.z, xv.x, d0);
            d1 = fmaf(m.z, xv.y, d1);
        }
    }
    uint_t ps = ((uint_t)f2bf(s1) << 16) | (uint_t)f2bf(s0);
    uint_t pd = ((uint_t)f2bf(d1) << 16) | (uint_t)f2bf(d0);
    *(uint_t*)(g_agg + (size_t)node * 256 + lane * 2) = ps;
    *(uint_t*)(g_agg + (size_t)node * 256 + 128 + lane * 2) = pd;
}

// ---------------- MFMA GEMM: C = act(A[M][K]bf16 @ B + bias) ----------------
// LAYER 0: g_h1 = relu(g_agg @ g_bp1 + g_bc1), K=256, N=128
// LAYER 1: g_h2 = relu(g_agg @ g_bp2 + g_bc2), K=256, N=128
// LAYER 2: out  = g_h2 @ g_bp3 + g_bro, K=128, N=64 (dtype-flex store to outp)
// All global buffers resolved in DEVICE code (see note at g_* decls).
// Verified layouts: A[m=lane&15][k=(lane>>4)*8+j]; B[k=(lane>>4)*8+j][n=lane&15];
//                   C col=lane&15, row=(lane>>4)*4+reg.

template <int LAYER, int KB, int NN, int NT, int RELU>
__global__ __launch_bounds__(256) void gemm_mfma(void* __restrict__ outp) {
    const ushort_t* A = (LAYER == 2) ? g_h2 : g_agg;
    const ushort_t* Bp = (LAYER == 0) ? g_bp1 : (LAYER == 1) ? g_bp2 : g_bp3;
    const float* bias = (LAYER == 0) ? g_bc1 : (LAYER == 1) ? g_bc2 : g_bro;
    const int M = N_NODES;
    const int K = KB * 32;
    int w = threadIdx.x >> 6; // wave 0..3
    int lane = threadIdx.x & 63;
    int c = lane & 15;
    int q = lane >> 4;
    int mBase = blockIdx.x * 64 + w * 16;

    f32x4 acc[NT];
#pragma unroll
    for (int nt = 0; nt < NT; nt++) acc[nt] = {0.f, 0.f, 0.f, 0.f};

    int arow = mBase + c;
    if (arow >= M) arow = M - 1; // clamp; stores guarded

#pragma unroll
    for (int kb = 0; kb < KB; kb++) {
        bf16x8 a = *(const bf16x8*)(A + (size_t)arow * K + kb * 32 + q * 8);
#pragma unroll
        for (int nt = 0; nt < NT; nt++) {
            bf16x8 b = *(const bf16x8*)(Bp + (((kb * NN + nt * 16 + c) << 5) + q * 8));
            acc[nt] = __builtin_amdgcn_mfma_f32_16x16x32_bf16(a, b, acc[nt], 0, 0, 0);
        }
    }

    int is16 = (LAYER == 2) ? g_is16 : 1;
#pragma unroll
    for (int nt = 0; nt < NT; nt++) {
        int n = nt * 16 + c;
        float bi = bias[n];
#pragma unroll
        for (int r = 0; r < 4; r++) {
            int m = mBase + q * 4 + r;
            if (m >= M) continue;
            float v = acc[nt][r] + bi;
            if (RELU) v = fmaxf(v, 0.f);
            if (LAYER == 0)
                g_h1[(size_t)m * NN + n] = f2bf(v);
            else if (LAYER == 1)
                g_h2[(size_t)m * NN + n] = f2bf(v);
            else if (is16)
                ((ushort_t*)outp)[(size_t)m * NN + n] = f2bf(v);
            else
                ((float*)outp)[(size_t)m * NN + n] = v;
        }
    }
}

// ---------------- launch ----------------

static inline int cdiv(int a, int b) { return (a + b - 1) / b; }

extern "C" void kernel_launch(void* const* d_in, const int* in_sizes, int n_in,
                              void* d_out, int out_size, void* d_ws, size_t ws_size,
                              hipStream_t stream) {
    const void* x = d_in[0]; // [50000][128]
    const int* eidx = (const int*)d_in[1];
    const void* theta = d_in[2];
    const void* W1s = d_in[3];
    const void* W1d = d_in[4];
    const void* b1s = d_in[5];
    const void* b1d = d_in[6];
    const void* W2s = d_in[7];
    const void* W2d = d_in[8];
    const void* b2s = d_in[9];
    const void* b2d = d_in[10];
    const void* Wro = d_in[11];
    const void* bro = d_in[12];
    (void)in_sizes; (void)n_in; (void)out_size; (void)d_ws; (void)ws_size;

    const int NB = cdiv(N_NODES, 1024); // 49

    detect_kernel<<<1, 64, 0, stream>>>((const uint_t*)x, eidx);
    init_nodes<<<cdiv(N_NODES, 256), 256, 0, stream>>>();
    edge_pass<<<cdiv(N_EDGES, 256), 256, 0, stream>>>(eidx, (const ushort_t*)theta, (const float*)theta);
    scan1<<<NB, 1024, 0, stream>>>();
    scan2<<<1, 1, 0, stream>>>(NB);
    scan3<<<cdiv(N_NODES, 256), 256, 0, stream>>>();
    fill_raw<<<cdiv(N_EDGES, 256), 256, 0, stream>>>(eidx);
    fill_self<<<cdiv(N_NODES, 256), 256, 0, stream>>>();
    deg_pass<<<cdiv(N_NODES, 256), 256, 0, stream>>>();
    finalize_w<<<cdiv(CSR_E, 256), 256, 0, stream>>>();
    prep_wc<<<cdiv(256 * 128, 256), 256, 0, stream>>>((const ushort_t*)W1s, (const float*)W1s,
                                                      (const ushort_t*)W1d, (const float*)W1d,
                                                      (const ushort_t*)b1s, (const float*)b1s,
                                                      (const ushort_t*)b1d, (const float*)b1d, 0);
    prep_wc<<<cdiv(256 * 128, 256), 256, 0, stream>>>((const ushort_t*)W2s, (const float*)W2s,
                                                      (const ushort_t*)W2d, (const float*)W2d,
                                                      (const ushort_t*)b2s, (const float*)b2s,
                                                      (const ushort_t*)b2d, (const float*)b2d, 1);
    prep_ro<<<cdiv(128 * 64, 256), 256, 0, stream>>>((const ushort_t*)Wro, (const float*)Wro,
                                                     (const ushort_t*)bro, (const float*)bro);

    const int GB = cdiv(N_NODES, 64); // 782
    // layer 1
    aggregate_kernel<<<cdiv(N_NODES, 4), 256, 0, stream>>>((const ushort_t*)x, (const float*)x, 1);
    gemm_mfma<0, 8, 128, 8, 1><<<GB, 256, 0, stream>>>(nullptr);
    // layer 2
    aggregate_kernel<<<cdiv(N_NODES, 4), 256, 0, stream>>>(nullptr, nullptr, 0);
    gemm_mfma<1, 8, 128, 8, 1><<<GB, 256, 0, stream>>>(nullptr);
    // readout
    gemm_mfma<2, 4, 64, 4, 0><<<GB, 256, 0, stream>>>(d_out);
}

// Round 6
// 427.950 us; speedup vs baseline: 1.4439x; 1.0904x over previous
//
#include <hip/hip_runtime.h>

#define N_NODES 50000
#define N_EDGES 400000
#define CSR_E (2 * N_EDGES + N_NODES) /* 850000 */
#define OUT_N (N_NODES * 64)

typedef unsigned short ushort_t;
typedef unsigned int uint_t;
typedef __attribute__((ext_vector_type(8))) short bf16x8;
typedef __attribute__((ext_vector_type(4))) float f32x4;

__device__ __forceinline__ float bf2f(ushort_t u) {
    return __uint_as_float(((uint_t)u) << 16);
}
__device__ __forceinline__ ushort_t f2bf(float f) {
    uint_t b = __float_as_uint(f);
    b += 0x7FFFu + ((b >> 16) & 1u); // RNE
    return (ushort_t)(b >> 16);
}

// ---------------- static device scratch (module BSS; d_ws untouched) ----------------
// NOTE: these symbols must ONLY be referenced from device code. Passing them as
// kernel arguments from host passes the host shadow address -> GPU fault (round 4).

__device__ int g_est;  // edge-index word stride: 1 = int32, 2 = int64
__device__ int g_is16; // 1 = float tensors bf16-packed, 0 = fp32
__device__ float g_dis_s[N_NODES];
__device__ float g_dis_r[N_NODES];
__device__ float g_c2[N_EDGES];
__device__ float g_s2[N_EDGES];
__device__ int g_count[N_NODES];
__device__ int g_offs[N_NODES];
__device__ int g_cursor[N_NODES];
__device__ int g_bsum[64];
__device__ int g_bbase[64];
__device__ __align__(16) float4 g_csr[CSR_E]; // raw: (src,out,in,dst) -> final: (src,wS,wD,0)
__device__ __align__(16) ushort_t g_agg[(size_t)N_NODES * 256]; // bf16 [N][s128|d128]
__device__ __align__(16) ushort_t g_h1[(size_t)N_NODES * 128];  // bf16
__device__ __align__(16) ushort_t g_h2[(size_t)N_NODES * 128];  // bf16
__device__ __align__(16) ushort_t g_bp1[8 * 128 * 32]; // B packed [kb][n][kk] bf16
__device__ __align__(16) ushort_t g_bp2[8 * 128 * 32];
__device__ __align__(16) ushort_t g_bp3[4 * 64 * 32];
__device__ float g_bc1[128];
__device__ float g_bc2[128];
__device__ float g_bro[64];

// ---------------- dtype / index-width detection ----------------

__global__ void detect_kernel(const uint_t* __restrict__ xw, const int* __restrict__ eidx) {
    if (threadIdx.x == 0 && blockIdx.x == 0) {
        int cnt = 0;
        for (int i = 0; i < 64; i++) {
            uint_t w = xw[i];
            int elo = (w >> 7) & 0xFF;
            if (elo >= 100 && elo <= 150) cnt++;
        }
        g_is16 = (cnt >= 48) ? 1 : 0;
        int any = 0;
        for (int i = 1; i < 128; i += 2) any |= eidx[i];
        g_est = any ? 1 : 2;
    }
}

// ---------------- graph prep ----------------

__global__ __launch_bounds__(256) void init_nodes() {
    int i = blockIdx.x * 256 + threadIdx.x;
    if (i < N_NODES) g_count[i] = 1; // self-loop entry
}

__global__ __launch_bounds__(256) void edge_pass(const int* __restrict__ eidx,
                                                 const ushort_t* __restrict__ th16,
                                                 const float* __restrict__ th32) {
    int e = blockIdx.x * 256 + threadIdx.x;
    if (e >= N_EDGES) return;
    int st = g_est;
    int s = eidx[(size_t)e * st];
    int r = eidx[((size_t)N_EDGES + e) * st];
    float t = g_is16 ? bf2f(th16[e]) : th32[e];
    float sn, cs_;
    sincosf(t, &sn, &cs_);
    g_c2[e] = cs_ * cs_;
    g_s2[e] = sn * sn;
    // CSR bucket sizes keyed by destination cr: fwd dst=r, rev dst=s
    atomicAdd(&g_count[r], 1);
    atomicAdd(&g_count[s], 1);
}

// ---------------- exclusive scan over counts ----------------

__global__ __launch_bounds__(1024) void scan1() {
    __shared__ int sd[1024];
    int i = blockIdx.x * 1024 + threadIdx.x;
    int v = (i < N_NODES) ? g_count[i] : 0;
    sd[threadIdx.x] = v;
    __syncthreads();
    for (int o = 1; o < 1024; o <<= 1) {
        int tv = (threadIdx.x >= o) ? sd[threadIdx.x - o] : 0;
        __syncthreads();
        sd[threadIdx.x] += tv;
        __syncthreads();
    }
    if (i < N_NODES) g_offs[i] = sd[threadIdx.x] - v;
    if (threadIdx.x == 1023) g_bsum[blockIdx.x] = sd[1023];
}

__global__ void scan2(int nb) {
    if (blockIdx.x == 0 && threadIdx.x == 0) {
        int run = 0;
        for (int b = 0; b < nb; b++) {
            g_bbase[b] = run;
            run += g_bsum[b];
        }
    }
}

__global__ __launch_bounds__(256) void scan3() {
    int i = blockIdx.x * 256 + threadIdx.x;
    if (i < N_NODES) {
        int o = g_offs[i] + g_bbase[i >> 10];
        g_offs[i] = o;
        g_cursor[i] = o;
    }
}

// ---------------- raw CSR fill: (src, out_w, in_w, dst) ----------------

__global__ __launch_bounds__(256) void fill_raw(const int* __restrict__ eidx) {
    int e = blockIdx.x * 256 + threadIdx.x;
    if (e >= N_EDGES) return;
    int st = g_est;
    int s = eidx[(size_t)e * st];
    int r = eidx[((size_t)N_EDGES + e) * st];
    float c2 = g_c2[e], s2 = g_s2[e];
    // fwd: cs=s, cr=r, out=c2, in=s2
    {
        int p = atomicAdd(&g_cursor[r], 1);
        g_csr[p] = make_float4(__int_as_float(s), c2, s2, __int_as_float(r));
    }
    // rev: cs=r, cr=s, out=s2, in=c2
    {
        int p = atomicAdd(&g_cursor[s], 1);
        g_csr[p] = make_float4(__int_as_float(r), s2, c2, __int_as_float(s));
    }
}

__global__ __launch_bounds__(256) void fill_self() {
    int n = blockIdx.x * 256 + threadIdx.x;
    if (n >= N_NODES) return;
    int p = atomicAdd(&g_cursor[n], 1);
    g_csr[p] = make_float4(__int_as_float(n), 1.0f, 1.0f, __int_as_float(n));
}

// ---------------- degrees from buckets (atomic-free) ----------------
// pairing identity: deg_s[n] = sum of in_w over bucket n; deg_r[n] = sum of out_w.

__global__ __launch_bounds__(256) void deg_pass() {
    int n = blockIdx.x * 256 + threadIdx.x;
    if (n >= N_NODES) return;
    int off = g_offs[n], c = g_count[n];
    float ds = 0.f, dr = 0.f;
    for (int k = 0; k < c; k++) {
        float4 e = g_csr[off + k];
        ds += e.z; // in_w
        dr += e.y; // out_w
    }
    g_dis_s[n] = rsqrtf(ds + 1e-12f);
    g_dis_r[n] = rsqrtf(dr + 1e-12f);
}

// ---------------- finalize per-entry weights (ALPHA=0.5 folded) ----------------

__global__ __launch_bounds__(256) void finalize_w() {
    int i = blockIdx.x * 256 + threadIdx.x;
    if (i >= CSR_E) return;
    float4 e = g_csr[i];
    int m = __float_as_int(e.x); // src (cs)
    int n = __float_as_int(e.w); // dst (cr)
    float wS = 0.5f * g_dis_s[m] * e.y * g_dis_r[n];
    float wD = 0.5f * g_dis_r[m] * e.z * g_dis_s[n];
    g_csr[i] = make_float4(e.x, wS, wD, 0.0f);
}

// ---------------- weight packing for MFMA: Bp[kb][n][kk] bf16 ----------------

__global__ __launch_bounds__(256) void prep_wc(const ushort_t* Ws16, const float* Ws32,
                                               const ushort_t* Wd16, const float* Wd32,
                                               const ushort_t* bs16, const float* bs32,
                                               const ushort_t* bd16, const float* bd32,
                                               int layer) {
    ushort_t* Bp = layer ? g_bp2 : g_bp1;
    float* bc = layer ? g_bc2 : g_bc1;
    int is16 = g_is16;
    int i = blockIdx.x * 256 + threadIdx.x;
    if (i < 256 * 128) {
        int k = i >> 7, n = i & 127;
        ushort_t v;
        if (k < 128) {
            int idx = k * 128 + n;
            v = is16 ? Ws16[idx] : f2bf(Ws32[idx]);
        } else {
            int idx = (k - 128) * 128 + n;
            v = is16 ? Wd16[idx] : f2bf(Wd32[idx]);
        }
        int kb = k >> 5, kk = k & 31;
        Bp[((kb * 128 + n) << 5) + kk] = v;
    }
    if (i < 128) {
        float a = is16 ? bf2f(bs16[i]) : bs32[i];
        float b = is16 ? bf2f(bd16[i]) : bd32[i];
        bc[i] = 0.5f * (a + b);
    }
}

__global__ __launch_bounds__(256) void prep_ro(const ushort_t* W16, const float* W32,
                                               const ushort_t* b16, const float* b32) {
    int is16 = g_is16;
    int i = blockIdx.x * 256 + threadIdx.x;
    if (i < 128 * 64) {
        int k = i >> 6, n = i & 63;
        ushort_t v = is16 ? W16[i] : f2bf(W32[i]);
        int kb = k >> 5, kk = k & 31;
        g_bp3[((kb * 64 + n) << 5) + kk] = v;
    }
    if (i < 64) g_bro[i] = is16 ? bf2f(b16[i]) : b32[i];
}

// ---------------- aggregation: one wave per node, lane owns 2 features ----------------
// ext=1: input external x (dtype-flex); ext=0: input g_h1 (bf16). Output g_agg bf16 [N][256].
// Unrolled x8: batch 8 independent CSR loads, then 8 independent row gathers ->
// MLP ~8 per wave instead of 1 (round-5 counters: 2.3 TB/s == 1 outstanding
// 256B row x ~5600 waves / ~600ns; latency-bound, not BW-bound).

__global__ __launch_bounds__(256) void aggregate_kernel(const ushort_t* __restrict__ x16,
                                                        const float* __restrict__ x32, int ext) {
    int node = blockIdx.x * 4 + (threadIdx.x >> 6);
    if (node >= N_NODES) return;
    int lane = threadIdx.x & 63;
    int off = g_offs[node];
    int c = g_count[node];
    float s0 = 0.f, s1 = 0.f, d0 = 0.f, d1 = 0.f;
    if (!ext || g_is16) {
        const ushort_t* xin = ext ? x16 : g_h1;
        int k = 0;
        for (; k + 8 <= c; k += 8) {
            float4 e[8];
#pragma unroll
            for (int j = 0; j < 8; j++) e[j] = g_csr[off + k + j];
            uint_t v[8];
#pragma unroll
            for (int j = 0; j < 8; j++) {
                int src = __float_as_int(e[j].x);
                v[j] = *(const uint_t*)(xin + (size_t)src * 128 + lane * 2);
            }
#pragma unroll
            for (int j = 0; j < 8; j++) {
                float x0 = bf2f((ushort_t)(v[j] & 0xffffu));
                float x1 = bf2f((ushort_t)(v[j] >> 16));
                s0 = fmaf(e[j].y, x0, s0);
                s1 = fmaf(e[j].y, x1, s1);
                d0 = fmaf(e[j].z, x0, d0);
                d1 = fmaf(e[j].z, x1, d1);
            }
        }
        for (; k < c; k++) {
            float4 m = g_csr[off + k];
            int src = __float_as_int(m.x);
            uint_t v = *(const uint_t*)(xin + (size_t)src * 128 + lane * 2);
            float x0 = bf2f((ushort_t)(v & 0xffffu));
            float x1 = bf2f((ushort_t)(v >> 16));
            s0 = fmaf(m.y, x0, s0);
            s1 = fmaf(m.y, x1, s1);
            d0 = fmaf(m.z, x0, d0);
            d1 = fmaf(m.z, x1, d1);
        }
    } else {
        for (int k = 0; k < c; k++) {
            float4 m = g_csr[off + k];
            int src = __float_as_int(m.x);
            float2 xv = *(const float2*)(x32 + (size_t)src * 128 + lane * 2);
            s0 = fmaf(m.y, xv.x, s0);
            s1 = fmaf(m.y, xv.y, s1);
            d0 = fmaf(m.z, xv.x, d0);
            d1 = fmaf(m.z, xv.y, d1);
        }
    }
    uint_t ps = ((uint_t)f2bf(s1) << 16) | (uint_t)f2bf(s0);
    uint_t pd = ((uint_t)f2bf(d1) << 16) | (uint_t)f2bf(d0);
    *(uint_t*)(g_agg + (size_t)node * 256 + lane * 2) = ps;
    *(uint_t*)(g_agg + (size_t)node * 256 + 128 + lane * 2) = pd;
}

// ---------------- MFMA GEMM: C = act(A[M][K]bf16 @ B + bias) ----------------
// LAYER 0: g_h1 = relu(g_agg @ g_bp1 + g_bc1), K=256, N=128
// LAYER 1: g_h2 = relu(g_agg @ g_bp2 + g_bc2), K=256, N=128
// LAYER 2: out  = g_h2 @ g_bp3 + g_bro, K=128, N=64 (dtype-flex store to outp)
// All global buffers resolved in DEVICE code (see note at g_* decls).
// Verified layouts: A[m=lane&15][k=(lane>>4)*8+j]; B[k=(lane>>4)*8+j][n=lane&15];
//                   C col=lane&15, row=(lane>>4)*4+reg.

template <int LAYER, int KB, int NN, int NT, int RELU>
__global__ __launch_bounds__(256) void gemm_mfma(void* __restrict__ outp) {
    const ushort_t* A = (LAYER == 2) ? g_h2 : g_agg;
    const ushort_t* Bp = (LAYER == 0) ? g_bp1 : (LAYER == 1) ? g_bp2 : g_bp3;
    const float* bias = (LAYER == 0) ? g_bc1 : (LAYER == 1) ? g_bc2 : g_bro;
    const int M = N_NODES;
    const int K = KB * 32;
    int w = threadIdx.x >> 6; // wave 0..3
    int lane = threadIdx.x & 63;
    int c = lane & 15;
    int q = lane >> 4;
    int mBase = blockIdx.x * 64 + w * 16;

    f32x4 acc[NT];
#pragma unroll
    for (int nt = 0; nt < NT; nt++) acc[nt] = {0.f, 0.f, 0.f, 0.f};

    int arow = mBase + c;
    if (arow >= M) arow = M - 1; // clamp; stores guarded

#pragma unroll
    for (int kb = 0; kb < KB; kb++) {
        bf16x8 a = *(const bf16x8*)(A + (size_t)arow * K + kb * 32 + q * 8);
#pragma unroll
        for (int nt = 0; nt < NT; nt++) {
            bf16x8 b = *(const bf16x8*)(Bp + (((kb * NN + nt * 16 + c) << 5) + q * 8));
            acc[nt] = __builtin_amdgcn_mfma_f32_16x16x32_bf16(a, b, acc[nt], 0, 0, 0);
        }
    }

    int is16 = (LAYER == 2) ? g_is16 : 1;
#pragma unroll
    for (int nt = 0; nt < NT; nt++) {
        int n = nt * 16 + c;
        float bi = bias[n];
#pragma unroll
        for (int r = 0; r < 4; r++) {
            int m = mBase + q * 4 + r;
            if (m >= M) continue;
            float v = acc[nt][r] + bi;
            if (RELU) v = fmaxf(v, 0.f);
            if (LAYER == 0)
                g_h1[(size_t)m * NN + n] = f2bf(v);
            else if (LAYER == 1)
                g_h2[(size_t)m * NN + n] = f2bf(v);
            else if (is16)
                ((ushort_t*)outp)[(size_t)m * NN + n] = f2bf(v);
            else
                ((float*)outp)[(size_t)m * NN + n] = v;
        }
    }
}

// ---------------- launch ----------------

static inline int cdiv(int a, int b) { return (a + b - 1) / b; }

extern "C" void kernel_launch(void* const* d_in, const int* in_sizes, int n_in,
                              void* d_out, int out_size, void* d_ws, size_t ws_size,
                              hipStream_t stream) {
    const void* x = d_in[0]; // [50000][128]
    const int* eidx = (const int*)d_in[1];
    const void* theta = d_in[2];
    const void* W1s = d_in[3];
    const void* W1d = d_in[4];
    const void* b1s = d_in[5];
    const void* b1d = d_in[6];
    const void* W2s = d_in[7];
    const void* W2d = d_in[8];
    const void* b2s = d_in[9];
    const void* b2d = d_in[10];
    const void* Wro = d_in[11];
    const void* bro = d_in[12];
    (void)in_sizes; (void)n_in; (void)out_size; (void)d_ws; (void)ws_size;

    const int NB = cdiv(N_NODES, 1024); // 49

    detect_kernel<<<1, 64, 0, stream>>>((const uint_t*)x, eidx);
    init_nodes<<<cdiv(N_NODES, 256), 256, 0, stream>>>();
    edge_pass<<<cdiv(N_EDGES, 256), 256, 0, stream>>>(eidx, (const ushort_t*)theta, (const float*)theta);
    scan1<<<NB, 1024, 0, stream>>>();
    scan2<<<1, 1, 0, stream>>>(NB);
    scan3<<<cdiv(N_NODES, 256), 256, 0, stream>>>();
    fill_raw<<<cdiv(N_EDGES, 256), 256, 0, stream>>>(eidx);
    fill_self<<<cdiv(N_NODES, 256), 256, 0, stream>>>();
    deg_pass<<<cdiv(N_NODES, 256), 256, 0, stream>>>();
    finalize_w<<<cdiv(CSR_E, 256), 256, 0, stream>>>();
    prep_wc<<<cdiv(256 * 128, 256), 256, 0, stream>>>((const ushort_t*)W1s, (const float*)W1s,
                                                      (const ushort_t*)W1d, (const float*)W1d,
                                                      (const ushort_t*)b1s, (const float*)b1s,
                                                      (const ushort_t*)b1d, (const float*)b1d, 0);
    prep_wc<<<cdiv(256 * 128, 256), 256, 0, stream>>>((const ushort_t*)W2s, (const float*)W2s,
                                                      (const ushort_t*)W2d, (const float*)W2d,
                                                      (const ushort_t*)b2s, (const float*)b2s,
                                                      (const ushort_t*)b2d, (const float*)b2d, 1);
    prep_ro<<<cdiv(128 * 64, 256), 256, 0, stream>>>((const ushort_t*)Wro, (const float*)Wro,
                                                     (const ushort_t*)bro, (const float*)bro);

    const int GB = cdiv(N_NODES, 64); // 782
    // layer 1
    aggregate_kernel<<<cdiv(N_NODES, 4), 256, 0, stream>>>((const ushort_t*)x, (const float*)x, 1);
    gemm_mfma<0, 8, 128, 8, 1><<<GB, 256, 0, stream>>>(nullptr);
    // layer 2
    aggregate_kernel<<<cdiv(N_NODES, 4), 256, 0, stream>>>(nullptr, nullptr, 0);
    gemm_mfma<1, 8, 128, 8, 1><<<GB, 256, 0, stream>>>(nullptr);
    // readout
    gemm_mfma<2, 4, 64, 4, 0><<<GB, 256, 0, stream>>>(d_out);
}